// Round 6
// baseline (44.951 us; speedup 1.0000x reference)
//
#include <hip/hip_runtime.h>

// PatchManifoldLossPre: resize (8,19,512,512) -> (8,19,48,48) with jax.image.resize
// bilinear (antialias=True, triangle kernel, half-pixel centers), split into 4x4
// patches of 12x12, P[16, 21888], value = mean(weights * pairwise-MSD(P)).
// pairwise-MSD via Gram: map[a,b] = (G[aa]+G[bb]-2G[ab])/N.
//
// Round-6: round-5 structure (3648 small blocks, latency-optimized) with the
// per-block fp64 weight preamble ELIMINATED: the 48x22 triangle-kernel weight
// table is computed at COMPILE TIME (constexpr) into __constant__ memory.
// k_resize now has zero setup, one barrier, LDS = tile only (4.6 KB), 8 blk/CU.

#define HIN 512
#define WOUT 48
#define NTAP 22
#define NBC 152              // 8*19
#define NPAIR 24             // row-pairs per bc
#define NBLK (NBC * NPAIR)   // 3648 = 8 * 456
#define TSTRIDE 580          // swizzled LDS row stride in floats
#define GROUP 12             // patch size
#define KS (512.0 / 48.0)

// Compile-time triangle-kernel resize weights matching jax.image.resize
// (method="bilinear", antialias=True): sample s=(i+0.5)*KS-0.5, kernel scale KS,
// normalized over valid taps. Window clamped into [0, HIN-NTAP].
struct WTab {
  float hw[NTAP][WOUT];
  int hst[WOUT];
  constexpr WTab() : hw{}, hst{} {
    for (int i = 0; i < WOUT; ++i) {
      double s = (i + 0.5) * KS - 0.5;
      double v = s - KS;
      long long tt = (long long)v;                    // trunc toward zero
      int stc = (int)((v > (double)tt) ? tt + 1 : tt);  // ceil(v)
      if (stc < 0) stc = 0;
      if (stc > HIN - NTAP) stc = HIN - NTAP;
      double wr[NTAP] = {};
      double sum = 0.0;
      for (int k = 0; k < NTAP; ++k) {
        int j = stc + k;
        double d = s - (double)j;
        if (d < 0) d = -d;
        double wv = 1.0 - d * (1.0 / KS);
        if (wv < 0.0) wv = 0.0;
        if (j >= HIN) wv = 0.0;  // j<0 impossible after clamp
        wr[k] = wv;
        sum += wv;
      }
      for (int k = 0; k < NTAP; ++k) hw[k][i] = (float)(wr[k] / sum);
      hst[i] = stc;
    }
  }
};
__constant__ WTab WT{};

__global__ __launch_bounds__(256, 8) void k_resize(const float* __restrict__ pred,
                                                   float* __restrict__ smallimg,
                                                   float* __restrict__ G,
                                                   unsigned* __restrict__ ticket) {
  __shared__ float tile[2][TSTRIDE];  // 4640 B, swizzled (c -> c + 4*(c>>5))

  const int t = threadIdx.x;
  // XCD-chunked remap (bijective: 3648 = 8*456): round-robin XCD assignment gets
  // contiguous work chunks so row-adjacent pairs reuse that XCD's L2 tap rows.
  const int wid = (blockIdx.x & 7) * (NBLK / 8) + (blockIdx.x >> 3);
  const int bc = wid / NPAIR;
  const int pair = wid - bc * NPAIR;

  // Replace the memset dispatch: visible to k_gram_final at kernel boundary.
  if (blockIdx.x == 0) {
    G[t] = 0.f;
    if (t == 0) *ticket = 0u;
  }

  // ---- Vertical pass: thread = (output row slot, float4 column slice) ----
  const int slot = t >> 7;              // 0..1 (wave-uniform)
  const int oy = pair * 2 + slot;
  const int x = (t & 127) << 2;         // 0..508
  const int base = WT.hst[oy];
  const float* p = pred + (size_t)bc * (HIN * HIN) + (size_t)base * HIN + x;
  float4 a = make_float4(0.f, 0.f, 0.f, 0.f);
#pragma unroll
  for (int k = 0; k < NTAP; ++k) {
    const float4 v = *reinterpret_cast<const float4*>(p + (size_t)k * HIN);
    const float wk = WT.hw[k][oy];      // L1-resident 4.4 KB constant table
    a.x = fmaf(wk, v.x, a.x);
    a.y = fmaf(wk, v.y, a.y);
    a.z = fmaf(wk, v.z, a.z);
    a.w = fmaf(wk, v.w, a.w);
  }
  *reinterpret_cast<float4*>(&tile[slot][x + ((x >> 5) << 2)]) = a;
  __syncthreads();

  // ---- Horizontal gather (96 of 256 threads) -> smallimg ----
  if (t < 2 * WOUT) {
    const int r = (t >= WOUT) ? 1 : 0;
    const int j = t - r * WOUT;
    const int stc = WT.hst[j];
    float acc = 0.f;
#pragma unroll
    for (int k = 0; k < NTAP; ++k) {
      const int cc = stc + k;
      acc = fmaf(WT.hw[k][j], tile[r][cc + ((cc >> 5) << 2)], acc);
    }
    smallimg[(size_t)bc * (WOUT * WOUT) + (pair * 2 + r) * WOUT + j] = acc;
  }
}

// One block per (b,c): stage 48x48 image in LDS, thread owns pair (a,b), Gram via
// atomics into G; the LAST block (device-scope ticket) computes the final scalar.
__global__ __launch_bounds__(256) void k_gram_final(const float* __restrict__ smallimg,
                                                    const float* __restrict__ wts,
                                                    float* __restrict__ G,
                                                    unsigned* __restrict__ ticket,
                                                    float* __restrict__ out) {
  __shared__ float img[WOUT * WOUT];
  __shared__ float Gs[256];
  __shared__ float partial[4];
  __shared__ unsigned lastv;

  const int tid = threadIdx.x;
  const float* src = smallimg + (size_t)blockIdx.x * (WOUT * WOUT);
  for (int idx = tid; idx < (WOUT * WOUT) / 4; idx += 256) {
    *reinterpret_cast<float4*>(&img[idx * 4]) =
        *reinterpret_cast<const float4*>(src + idx * 4);
  }
  __syncthreads();
  const int a = tid >> 4;
  const int b = tid & 15;
  const float* pa = &img[((a >> 2) * GROUP) * WOUT + (a & 3) * GROUP];
  const float* pb = &img[((b >> 2) * GROUP) * WOUT + (b & 3) * GROUP];
  float acc = 0.f;
  for (int y = 0; y < GROUP; ++y) {
#pragma unroll
    for (int q = 0; q < 3; ++q) {
      const float4 va = *reinterpret_cast<const float4*>(pa + y * WOUT + q * 4);
      const float4 vb = *reinterpret_cast<const float4*>(pb + y * WOUT + q * 4);
      acc += va.x * vb.x + va.y * vb.y + va.z * vb.z + va.w * vb.w;
    }
  }
  atomicAdd(&G[tid], acc);
  __threadfence();   // release: G-atomics ordered before the ticket increment
  __syncthreads();   // all 256 lanes' atomics issued+fenced before tid 0 tickets
  if (tid == 0) lastv = atomicAdd(ticket, 1u);
  __syncthreads();
  if (lastv != NBC - 1) return;

  // Last block: coherent readback of G (device-scope atomic read), then reduce.
  __threadfence();
  Gs[tid] = atomicAdd(&G[tid], 0.f);
  __syncthreads();
  float v = wts[tid] * (Gs[a * 17] + Gs[b * 17] - 2.0f * Gs[tid]);
#pragma unroll
  for (int off = 32; off > 0; off >>= 1) v += __shfl_down(v, off, 64);
  if ((tid & 63) == 0) partial[tid >> 6] = v;
  __syncthreads();
  if (tid == 0) {
    out[0] = (partial[0] + partial[1] + partial[2] + partial[3]) *
             (float)(1.0 / (256.0 * 21888.0));
  }
}

extern "C" void kernel_launch(void* const* d_in, const int* in_sizes, int n_in,
                              void* d_out, int out_size, void* d_ws, size_t ws_size,
                              hipStream_t stream) {
  const float* pred = (const float*)d_in[0];
  const float* wts = (const float*)d_in[1];
  float* out = (float*)d_out;
  float* G = (float*)d_ws;                              // bytes [0, 1024)
  unsigned* ticket = (unsigned*)((char*)d_ws + 1024);   // bytes [1024, 1028)
  float* smallimg = (float*)((char*)d_ws + 2048);       // 152*48*48 floats

  hipLaunchKernelGGL(k_resize, dim3(NBLK), dim3(256), 0, stream,
                     pred, smallimg, G, ticket);
  hipLaunchKernelGGL(k_gram_final, dim3(NBC), dim3(256), 0, stream,
                     smallimg, wts, G, ticket, out);
}